// Round 17
// baseline (194.006 us; speedup 1.0000x reference)
//
#include <hip/hip_runtime.h>
#include <hip/hip_fp16.h>
#include <math.h>

#define N_NODES 50000
#define E_EDGES 400000
#define NEG_SLOPE 0.2f
#define SCAN_BLOCKS 250
#define SCAN_CHUNK 200

typedef _Float16 f16x8 __attribute__((ext_vector_type(8)));
typedef float f32x4 __attribute__((ext_vector_type(4)));

static inline int cdiv(long a, int b) { return (int)((a + b - 1) / b); }

__device__ __forceinline__ float lrelu(float v) {
    return v > 0.f ? v : NEG_SLOPE * v;
}

__device__ __forceinline__ void h4_to_f4(uint2 u, float o[4]) {
    union { uint2 u2; __half h[4]; } cv;
    cv.u2 = u;
    #pragma unroll
    for (int i = 0; i < 4; ++i) o[i] = __half2float(cv.h[i]);
}

// ---------------- prep: edge-count + layer-1 coef + weight transposes ----------------
// grid covers E_EDGES threads; blocks < cdiv(N,256) also do fold+coef; gid < 81920 does wt.
__global__ void k_prep(const int* __restrict__ ei, int* __restrict__ deg,
                       const float* __restrict__ x, const float* __restrict__ W1,
                       const float* __restrict__ a_src, const float* __restrict__ a_dst,
                       float* __restrict__ es, float* __restrict__ ed,
                       const float* __restrict__ W2, __half* __restrict__ W1t,
                       __half* __restrict__ W2t) {
    __shared__ float wesS[88], wedS[88];
    const int t = threadIdx.x;
    const int gid = blockIdx.x * blockDim.x + t;

    // edge degree count
    if (gid < E_EDGES) atomicAdd(&deg[ei[E_EDGES + gid]], 1);

    // weight transposes (fp16)
    if (gid < 512 * 32) {
        int n = gid >> 5, k = gid & 31;
        W1t[gid] = (k < 21) ? __float2half_rn(W1[k * 512 + n]) : __half(0.f);
    } else if (gid < 512 * 32 + 512 * 64) {
        int j = gid - 512 * 32;
        int k = j >> 6, n = j & 63;
        W2t[(size_t)n * 512 + k] = __float2half_rn(W2[j]);
    }

    // layer-1 coefficients (only blocks that own nodes)
    if (blockIdx.x < (N_NODES + 255) / 256) {
        if (t < 168) {
            int which = t / 84;
            int idx = t % 84;
            int k = idx >> 2, h = idx & 3;
            const float* a = which ? a_dst : a_src;
            float s = 0.f;
            for (int c = 0; c < 128; ++c)
                s += W1[k * 512 + h * 128 + c] * a[h * 128 + c];
            (which ? wedS : wesS)[idx] = s;
        }
        __syncthreads();

        int node = blockIdx.x * blockDim.x + t;
        if (node < N_NODES) {
            const float* xr = x + (size_t)node * 21;
            float e1[4] = {0.f, 0.f, 0.f, 0.f}, e2[4] = {0.f, 0.f, 0.f, 0.f};
            #pragma unroll
            for (int k = 0; k < 21; ++k) {
                float xv = xr[k];
                float4 a = *(const float4*)&wesS[k * 4];
                float4 b = *(const float4*)&wedS[k * 4];
                e1[0] += xv * a.x; e1[1] += xv * a.y; e1[2] += xv * a.z; e1[3] += xv * a.w;
                e2[0] += xv * b.x; e2[1] += xv * b.y; e2[2] += xv * b.z; e2[3] += xv * b.w;
            }
            *(float4*)&es[node * 4] = make_float4(e1[0], e1[1], e1[2], e1[3]);
            *(float4*)&ed[node * 4] = make_float4(e2[0], e2[1], e2[2], e2[3]);
        }
    }
}

// ---------------- CSR scan ----------------
__global__ void k_scan1(const int* __restrict__ deg, int* __restrict__ bsum) {
    __shared__ int sd[256];
    int b = blockIdx.x, t = threadIdx.x;
    int lo = b * SCAN_CHUNK;
    int s = 0;
    for (int i = t; i < SCAN_CHUNK; i += 256) s += deg[lo + i];
    sd[t] = s;
    __syncthreads();
    for (int off = 128; off; off >>= 1) {
        if (t < off) sd[t] += sd[t + off];
        __syncthreads();
    }
    if (t == 0) bsum[b] = sd[0];
}

__global__ void k_scan2(int* __restrict__ bsum) {
    __shared__ int sd[256];
    int t = threadIdx.x;
    int v = (t < SCAN_BLOCKS) ? bsum[t] : 0;
    sd[t] = v;
    __syncthreads();
    for (int off = 1; off < 256; off <<= 1) {
        int u = (t >= off) ? sd[t - off] : 0;
        __syncthreads();
        sd[t] += u;
        __syncthreads();
    }
    if (t < SCAN_BLOCKS) bsum[t] = sd[t] - v;   // exclusive
}

__global__ void k_scan3(const int* __restrict__ deg, const int* __restrict__ bsum,
                        int* __restrict__ row_ptr) {
    __shared__ int sd[256];
    int b = blockIdx.x, t = threadIdx.x;
    int lo = b * SCAN_CHUNK;
    int v = (t < SCAN_CHUNK) ? deg[lo + t] : 0;
    sd[t] = v;
    __syncthreads();
    for (int off = 1; off < 256; off <<= 1) {
        int u = (t >= off) ? sd[t - off] : 0;
        __syncthreads();
        sd[t] += u;
        __syncthreads();
    }
    if (t < SCAN_CHUNK) row_ptr[lo + t] = bsum[b] + sd[t] - v;
}

// end-pointer scatter: atomicAdd on row_ptr itself; afterwards row_ptr[d] = segment end.
__global__ void k_scatter(const int* __restrict__ ei, int* __restrict__ row_ptr,
                          int* __restrict__ csr_src) {
    int e = blockIdx.x * blockDim.x + threadIdx.x;
    if (e >= E_EDGES) return;
    int src = ei[e], dst = ei[E_EDGES + e];
    int p = atomicAdd(&row_ptr[dst], 1);
    csr_src[p] = src;
}

// ---------------- layer-1 edge phase on RAW x -> y16 (skip-max softmax) ----------------
__global__ void k_edge_l1x(const int* __restrict__ row_ptr, const int* __restrict__ csr_src,
                           const float* __restrict__ x, const float* __restrict__ es,
                           const float* __restrict__ ed, __half* __restrict__ y16) {
    int wid = (blockIdx.x * blockDim.x + threadIdx.x) >> 6;
    int l = threadIdx.x & 63;
    if (wid >= N_NODES) return;
    const int dst = wid;
    const int hh = l >> 4, sub = l & 15;
    const int beg = dst ? row_ptr[dst - 1] : 0;
    const int end = row_ptr[dst];
    const float eddg = ed[dst * 4 + hh];
    const float self_v = lrelu(es[dst * 4 + hh] + eddg);

    float s = 0.f;
    for (int k = beg + sub; k < end; k += 16)
        s += __expf(lrelu(es[csr_src[k] * 4 + hh] + eddg));
    #pragma unroll
    for (int off = 1; off < 16; off <<= 1) s += __shfl_xor(s, off, 64);
    float p_self = __expf(self_v);
    s += p_self;
    float inv_s = 1.f / s;

    float ih[4], eh[4], ph[4];
    #pragma unroll
    for (int h = 0; h < 4; ++h) {
        ih[h] = __shfl(inv_s, h * 16, 64);
        eh[h] = __shfl(eddg, h * 16, 64);
        ph[h] = __shfl(p_self, h * 16, 64);
    }

    const int g = l / 21;
    const int c = l - g * 21;
    const bool act = (l < 63);

    float xdv = (act && g == 0) ? x[(size_t)dst * 21 + c] : 0.f;
    float acc[4];
    #pragma unroll
    for (int h = 0; h < 4; ++h) acc[h] = ph[h] * ih[h] * xdv;

    if (act) {
        int k = beg + g;
        for (; k + 3 < end; k += 6) {
            int s0 = csr_src[k], s1 = csr_src[k + 3];
            float4 e0 = *(const float4*)&es[s0 * 4];
            float4 e1 = *(const float4*)&es[s1 * 4];
            float x0 = x[(size_t)s0 * 21 + c];
            float x1 = x[(size_t)s1 * 21 + c];
            #pragma unroll
            for (int h = 0; h < 4; ++h) {
                float a0 = __expf(lrelu((&e0.x)[h] + eh[h])) * ih[h];
                float a1 = __expf(lrelu((&e1.x)[h] + eh[h])) * ih[h];
                acc[h] += a0 * x0 + a1 * x1;
            }
        }
        if (k < end) {
            int s0 = csr_src[k];
            float4 e0 = *(const float4*)&es[s0 * 4];
            float x0 = x[(size_t)s0 * 21 + c];
            #pragma unroll
            for (int h = 0; h < 4; ++h) {
                float a0 = __expf(lrelu((&e0.x)[h] + eh[h])) * ih[h];
                acc[h] += a0 * x0;
            }
        }
    }

    #pragma unroll
    for (int h = 0; h < 4; ++h) {
        float a1 = __shfl(acc[h], (l + 21) & 63, 64);
        float a2 = __shfl(acc[h], (l + 42) & 63, 64);
        acc[h] += a1 + a2;
    }
    if (l < 32) {
        #pragma unroll
        for (int h = 0; h < 4; ++h) {
            float v = (l < 21) ? acc[h] : 0.f;
            y16[(size_t)dst * 128 + h * 32 + l] = __float2half_rn(v);
        }
    }
}

// ---------------- fused layers 1-post + 2-GEMM via MFMA ----------------
__global__ void k_l12_fused(const __half* __restrict__ y16, const __half* __restrict__ W1t,
                            const float* __restrict__ b1, const __half* __restrict__ W2t,
                            const float* __restrict__ a_src, const float* __restrict__ a_dst,
                            __half* __restrict__ C16, float* __restrict__ es, float* __restrict__ ed) {
    __shared__ _Float16 As[32][520];
    __shared__ float p1s[32][4];
    __shared__ float p2s[32][4];

    const int t = threadIdx.x;
    const int l = t & 63;
    const int wv = t >> 6;
    const int row0 = blockIdx.x * 32;
    const int lr = l & 15;
    const int kg = l >> 4;

    const _Float16* Y = (const _Float16*)y16;
    const _Float16* B1 = (const _Float16*)W1t;

    int ra0 = row0 + lr;       ra0 = ra0 < N_NODES ? ra0 : N_NODES - 1;
    int ra1 = row0 + 16 + lr;  ra1 = ra1 < N_NODES ? ra1 : N_NODES - 1;

    f32x4 acc1[2][8];
    #pragma unroll
    for (int m = 0; m < 2; ++m)
        #pragma unroll
        for (int n = 0; n < 8; ++n) acc1[m][n] = (f32x4){0.f, 0.f, 0.f, 0.f};

    f16x8 a0 = *(const f16x8*)(Y + (size_t)ra0 * 128 + wv * 32 + kg * 8);
    f16x8 a1 = *(const f16x8*)(Y + (size_t)ra1 * 128 + wv * 32 + kg * 8);

    #pragma unroll
    for (int nt = 0; nt < 8; ++nt) {
        f16x8 bf = *(const f16x8*)(B1 + (size_t)(wv * 128 + nt * 16 + lr) * 32 + kg * 8);
        acc1[0][nt] = __builtin_amdgcn_mfma_f32_16x16x32_f16(a0, bf, acc1[0][nt], 0, 0, 0);
        acc1[1][nt] = __builtin_amdgcn_mfma_f32_16x16x32_f16(a1, bf, acc1[1][nt], 0, 0, 0);
    }

    float bb[8];
    #pragma unroll
    for (int nt = 0; nt < 8; ++nt) bb[nt] = b1[wv * 128 + nt * 16 + lr];

    #pragma unroll
    for (int m = 0; m < 2; ++m) {
        #pragma unroll
        for (int r = 0; r < 4; ++r) {
            int rl = m * 16 + kg * 4 + r;
            #pragma unroll
            for (int nt = 0; nt < 8; ++nt) {
                float v = acc1[m][nt][r] + bb[nt];
                v = v > 0.f ? v : __expf(v) - 1.f;
                As[rl][wv * 128 + nt * 16 + lr] = (_Float16)v;
            }
        }
    }
    __syncthreads();

    const _Float16* B2 = (const _Float16*)W2t;
    const int n_g = wv * 16 + lr;
    f32x4 acc2[2];
    acc2[0] = (f32x4){0.f, 0.f, 0.f, 0.f};
    acc2[1] = (f32x4){0.f, 0.f, 0.f, 0.f};

    for (int kb = 0; kb < 512; kb += 32) {
        f16x8 fa0 = *(const f16x8*)&As[lr][kb + kg * 8];
        f16x8 fa1 = *(const f16x8*)&As[16 + lr][kb + kg * 8];
        f16x8 bf = *(const f16x8*)(B2 + (size_t)n_g * 512 + kb + kg * 8);
        acc2[0] = __builtin_amdgcn_mfma_f32_16x16x32_f16(fa0, bf, acc2[0], 0, 0, 0);
        acc2[1] = __builtin_amdgcn_mfma_f32_16x16x32_f16(fa1, bf, acc2[1], 0, 0, 0);
    }

    const float asv = a_src[n_g];
    const float adv = a_dst[n_g];

    #pragma unroll
    for (int m = 0; m < 2; ++m) {
        #pragma unroll
        for (int r = 0; r < 4; ++r) {
            int rl = m * 16 + kg * 4 + r;
            int grow = row0 + rl;
            float cv = acc2[m][r];
            float p1 = cv * asv, p2 = cv * adv;
            #pragma unroll
            for (int off = 1; off < 16; off <<= 1) {
                p1 += __shfl_xor(p1, off, 64);
                p2 += __shfl_xor(p2, off, 64);
            }
            if (grow < N_NODES)
                C16[(size_t)grow * 64 + n_g] = __float2half_rn(cv);
            if (lr == 0) { p1s[rl][wv] = p1; p2s[rl][wv] = p2; }
        }
    }
    __syncthreads();

    if (t < 32) {
        int grow = row0 + t;
        if (grow < N_NODES) {
            es[grow] = p1s[t][0] + p1s[t][1] + p1s[t][2] + p1s[t][3];
            ed[grow] = p2s[t][0] + p2s[t][1] + p2s[t][2] + p2s[t][3];
        }
    }
}

// ---------------- Layer 2 edge phase + fused layer-3 GEMM/coef ----------------
__global__ void k_gat_edge_l2_l3(const int* __restrict__ row_ptr, const int* __restrict__ csr_src,
                                 const __half* __restrict__ h16, const float* __restrict__ es,
                                 const float* __restrict__ ed, const float* __restrict__ b,
                                 const float* __restrict__ W3, const float* __restrict__ a_src3,
                                 const float* __restrict__ a_dst3, float* __restrict__ h3,
                                 float* __restrict__ es3, float* __restrict__ ed3) {
    int wid = (blockIdx.x * blockDim.x + threadIdx.x) >> 6;
    int lane = threadIdx.x & 63;
    if (wid >= N_NODES) return;
    const int dst = wid;
    const int g = lane >> 4, sub = lane & 15;
    const int beg = dst ? row_ptr[dst - 1] : 0;
    const int end = row_ptr[dst];
    const float edd = ed[dst];
    const float self_v = lrelu(es[dst] + edd);

    float s = 0.f;
    for (int k = beg + lane; k < end; k += 64)
        s += __expf(lrelu(es[csr_src[k]] + edd));
    #pragma unroll
    for (int off = 32; off; off >>= 1) s += __shfl_xor(s, off, 64);
    float p_self = __expf(self_v);
    s += p_self;
    const float inv_s = 1.f / s;

    float acc[4] = {0.f, 0.f, 0.f, 0.f};
    if (g == 0) {
        uint2 r = *(const uint2*)(h16 + (size_t)dst * 64 + sub * 4);
        float hv[4]; h4_to_f4(r, hv);
        float a_self = p_self * inv_s;
        #pragma unroll
        for (int j = 0; j < 4; ++j) acc[j] = a_self * hv[j];
    }
    for (int k0 = beg; k0 < end; k0 += 4) {
        int k = k0 + g;
        if (k < end) {
            int src = csr_src[k];
            float alpha = __expf(lrelu(es[src] + edd)) * inv_s;
            uint2 r = *(const uint2*)(h16 + (size_t)src * 64 + sub * 4);
            float hv[4]; h4_to_f4(r, hv);
            #pragma unroll
            for (int j = 0; j < 4; ++j) acc[j] += alpha * hv[j];
        }
    }
    #pragma unroll
    for (int off = 16; off < 64; off <<= 1) {
        #pragma unroll
        for (int j = 0; j < 4; ++j) acc[j] += __shfl_xor(acc[j], off, 64);
    }

    float4 bv = *(const float4*)&b[sub * 4];
    float4 w3 = *(const float4*)&W3[sub * 4];
    float o0 = acc[0] + bv.x, o1 = acc[1] + bv.y, o2 = acc[2] + bv.z, o3 = acc[3] + bv.w;
    o0 = o0 > 0.f ? o0 : expm1f(o0);
    o1 = o1 > 0.f ? o1 : expm1f(o1);
    o2 = o2 > 0.f ? o2 : expm1f(o2);
    o3 = o3 > 0.f ? o3 : expm1f(o3);
    float pp = o0 * w3.x + o1 * w3.y + o2 * w3.z + o3 * w3.w;
    #pragma unroll
    for (int off = 1; off < 16; off <<= 1) pp += __shfl_xor(pp, off, 64);

    if (lane == 0) {
        h3[dst] = pp;
        es3[dst] = pp * a_src3[0];
        ed3[dst] = pp * a_dst3[0];
    }
}

// ---------------- layer 3 edge phase + mean (16 lanes per dst) ----------------
__global__ void k_gat_edge_c1_mean(const int* __restrict__ row_ptr, const int* __restrict__ csr_src,
                                   const float* __restrict__ h, const float* __restrict__ es,
                                   const float* __restrict__ ed, const float* __restrict__ b3,
                                   float* __restrict__ out) {
    __shared__ float sdata[256];
    const int t = threadIdx.x;
    const int gid = blockIdx.x * 256 + t;
    const int dst = gid >> 4;
    const int sub = t & 15;
    float val = 0.f;
    if (dst < N_NODES) {
        int beg = dst ? row_ptr[dst - 1] : 0;
        int end = row_ptr[dst];
        float edd = ed[dst];
        float s = 0.f, acc = 0.f;
        for (int k = beg + sub; k < end; k += 16) {
            int src = csr_src[k];
            float pv = __expf(lrelu(es[src] + edd));
            s += pv;
            acc += pv * h[src];
        }
        #pragma unroll
        for (int off = 1; off < 16; off <<= 1) {
            s += __shfl_xor(s, off, 64);
            acc += __shfl_xor(acc, off, 64);
        }
        if (sub == 0) {
            float p = __expf(lrelu(es[dst] + edd));
            s += p;
            acc += p * h[dst];
            val = acc / s;
        }
    }
    sdata[t] = val;
    __syncthreads();
    for (int sft = 128; sft > 0; sft >>= 1) {
        if (t < sft) sdata[t] += sdata[t + sft];
        __syncthreads();
    }
    if (t == 0) {
        float add = sdata[0] / (float)N_NODES;
        if (blockIdx.x == 0) add += b3[0];
        atomicAdd(out, add);
    }
}

extern "C" void kernel_launch(void* const* d_in, const int* in_sizes, int n_in,
                              void* d_out, int out_size, void* d_ws, size_t ws_size,
                              hipStream_t stream) {
    const float* x      = (const float*)d_in[0];
    const float* W1     = (const float*)d_in[1];
    const float* a_src1 = (const float*)d_in[2];
    const float* a_dst1 = (const float*)d_in[3];
    const float* b1     = (const float*)d_in[4];
    const float* W2     = (const float*)d_in[5];
    const float* a_src2 = (const float*)d_in[6];
    const float* a_dst2 = (const float*)d_in[7];
    const float* b2     = (const float*)d_in[8];
    const float* W3     = (const float*)d_in[9];
    const float* a_src3 = (const float*)d_in[10];
    const float* a_dst3 = (const float*)d_in[11];
    const float* b3     = (const float*)d_in[12];
    const int*   ei     = (const int*)d_in[13];
    float* out = (float*)d_out;

    const int BS = 256;
    const size_t N = N_NODES;

    // workspace layout (float units)
    float*  ws      = (float*)d_ws;
    __half* y16     = (__half*)ws;                 // N*128 halves = N*64 floats
    __half* h2_16   = (__half*)(ws + N * 64);      // N*64 halves = N*32 floats
    float*  h3raw   = ws + N * 96;                 // N
    float*  es3     = h3raw + N;                   // N
    float*  ed3     = es3 + N;                     // N
    float*  es_buf  = ed3 + N;                     // N*4
    float*  ed_buf  = es_buf + N * 4;              // N*4
    __half* W1t     = (__half*)(ed_buf + N * 4);   // 512*32 halves = 8192 floats
    __half* W2t     = (__half*)(ed_buf + N * 4 + 8192); // 64*512 halves = 16384 floats
    int*    deg     = (int*)(ed_buf + N * 4 + 8192 + 16384); // N
    int*    row_ptr = deg + N;                     // N (end-pointer convention)
    int*    csr_src = row_ptr + N;                 // E_EDGES
    int*    bsum    = csr_src + E_EDGES;           // 256

    // prep: degree count + layer-1 coef + weight transposes (one kernel)
    hipMemsetAsync(deg, 0, N * sizeof(int), stream);
    k_prep<<<cdiv(E_EDGES, BS), BS, 0, stream>>>(ei, deg, x, W1, a_src1, a_dst1,
                                                 es_buf, ed_buf, W2, W1t, W2t);

    // CSR scan + end-pointer scatter
    k_scan1<<<SCAN_BLOCKS, 256, 0, stream>>>(deg, bsum);
    k_scan2<<<1, 256, 0, stream>>>(bsum);
    k_scan3<<<SCAN_BLOCKS, 256, 0, stream>>>(deg, bsum, row_ptr);
    k_scatter<<<cdiv(E_EDGES, BS), BS, 0, stream>>>(ei, row_ptr, csr_src);

    // Layer 1 edge aggregation on raw x
    k_edge_l1x<<<cdiv((long)N * 64, BS), BS, 0, stream>>>(row_ptr, csr_src, x, es_buf, ed_buf, y16);

    // Fused: out1 = ELU(y@W1+b1) (LDS) then h2 = out1@W2 + es/ed
    k_l12_fused<<<cdiv(N_NODES, 32), 256, 0, stream>>>(y16, W1t, b1, W2t, a_src2, a_dst2, h2_16, es_buf, ed_buf);

    // Layer 2 edge phase with fused layer-3 GEMM + coefficients
    k_gat_edge_l2_l3<<<cdiv((long)N * 64, BS), BS, 0, stream>>>(row_ptr, csr_src, h2_16, es_buf, ed_buf,
                                                                b2, W3, a_src3, a_dst3, h3raw, es3, ed3);

    // Layer 3 edge phase + mean
    hipMemsetAsync(out, 0, sizeof(float), stream);
    k_gat_edge_c1_mean<<<cdiv((long)N * 16, BS), BS, 0, stream>>>(row_ptr, csr_src, h3raw, es3, ed3, b3, out);
}

// Round 18
// 169.649 us; speedup vs baseline: 1.1436x; 1.1436x over previous
//
#include <hip/hip_runtime.h>
#include <hip/hip_fp16.h>
#include <math.h>

#define N_NODES 50000
#define E_EDGES 400000
#define NEG_SLOPE 0.2f
#define SCAN_BLOCKS 250
#define SCAN_CHUNK 200

typedef _Float16 f16x8 __attribute__((ext_vector_type(8)));
typedef float f32x4 __attribute__((ext_vector_type(4)));

static inline int cdiv(long a, int b) { return (int)((a + b - 1) / b); }

__device__ __forceinline__ float lrelu(float v) {
    return v > 0.f ? v : NEG_SLOPE * v;
}

__device__ __forceinline__ void h4_to_f4(uint2 u, float o[4]) {
    union { uint2 u2; __half h[4]; } cv;
    cv.u2 = u;
    #pragma unroll
    for (int i = 0; i < 4; ++i) o[i] = __half2float(cv.h[i]);
}

// ---------------- prep: edge-count + layer-1 coef + weight transposes ----------------
__global__ void k_prep(const int* __restrict__ ei, int* __restrict__ deg,
                       const float* __restrict__ x, const float* __restrict__ W1,
                       const float* __restrict__ a_src, const float* __restrict__ a_dst,
                       float* __restrict__ es, float* __restrict__ ed,
                       const float* __restrict__ W2, __half* __restrict__ W1t,
                       __half* __restrict__ W2t) {
    __shared__ float wesS[88], wedS[88];
    const int t = threadIdx.x;
    const int gid = blockIdx.x * blockDim.x + t;

    if (gid < E_EDGES) atomicAdd(&deg[ei[E_EDGES + gid]], 1);

    if (gid < 512 * 32) {
        int n = gid >> 5, k = gid & 31;
        W1t[gid] = (k < 21) ? __float2half_rn(W1[k * 512 + n]) : __half(0.f);
    } else if (gid < 512 * 32 + 512 * 64) {
        int j = gid - 512 * 32;
        int k = j >> 6, n = j & 63;
        W2t[(size_t)n * 512 + k] = __float2half_rn(W2[j]);
    }

    if (blockIdx.x < (N_NODES + 255) / 256) {
        if (t < 168) {
            int which = t / 84;
            int idx = t % 84;
            int k = idx >> 2, h = idx & 3;
            const float* a = which ? a_dst : a_src;
            float s = 0.f;
            for (int c = 0; c < 128; ++c)
                s += W1[k * 512 + h * 128 + c] * a[h * 128 + c];
            (which ? wedS : wesS)[idx] = s;
        }
        __syncthreads();

        int node = blockIdx.x * blockDim.x + t;
        if (node < N_NODES) {
            const float* xr = x + (size_t)node * 21;
            float e1[4] = {0.f, 0.f, 0.f, 0.f}, e2[4] = {0.f, 0.f, 0.f, 0.f};
            #pragma unroll
            for (int k = 0; k < 21; ++k) {
                float xv = xr[k];
                float4 a = *(const float4*)&wesS[k * 4];
                float4 b = *(const float4*)&wedS[k * 4];
                e1[0] += xv * a.x; e1[1] += xv * a.y; e1[2] += xv * a.z; e1[3] += xv * a.w;
                e2[0] += xv * b.x; e2[1] += xv * b.y; e2[2] += xv * b.z; e2[3] += xv * b.w;
            }
            *(float4*)&es[node * 4] = make_float4(e1[0], e1[1], e1[2], e1[3]);
            *(float4*)&ed[node * 4] = make_float4(e2[0], e2[1], e2[2], e2[3]);
        }
    }
}

// ---------------- CSR scan ----------------
__global__ void k_scan1(const int* __restrict__ deg, int* __restrict__ bsum) {
    __shared__ int sd[256];
    int b = blockIdx.x, t = threadIdx.x;
    int lo = b * SCAN_CHUNK;
    int s = 0;
    for (int i = t; i < SCAN_CHUNK; i += 256) s += deg[lo + i];
    sd[t] = s;
    __syncthreads();
    for (int off = 128; off; off >>= 1) {
        if (t < off) sd[t] += sd[t + off];
        __syncthreads();
    }
    if (t == 0) bsum[b] = sd[0];
}

__global__ void k_scan2(int* __restrict__ bsum) {
    __shared__ int sd[256];
    int t = threadIdx.x;
    int v = (t < SCAN_BLOCKS) ? bsum[t] : 0;
    sd[t] = v;
    __syncthreads();
    for (int off = 1; off < 256; off <<= 1) {
        int u = (t >= off) ? sd[t - off] : 0;
        __syncthreads();
        sd[t] += u;
        __syncthreads();
    }
    if (t < SCAN_BLOCKS) bsum[t] = sd[t] - v;   // exclusive
}

__global__ void k_scan3(const int* __restrict__ deg, const int* __restrict__ bsum,
                        int* __restrict__ row_ptr) {
    __shared__ int sd[256];
    int b = blockIdx.x, t = threadIdx.x;
    int lo = b * SCAN_CHUNK;
    int v = (t < SCAN_CHUNK) ? deg[lo + t] : 0;
    sd[t] = v;
    __syncthreads();
    for (int off = 1; off < 256; off <<= 1) {
        int u = (t >= off) ? sd[t - off] : 0;
        __syncthreads();
        sd[t] += u;
        __syncthreads();
    }
    if (t < SCAN_CHUNK) row_ptr[lo + t] = bsum[b] + sd[t] - v;
}

// end-pointer scatter: atomicAdd on row_ptr itself; afterwards row_ptr[d] = segment end.
__global__ void k_scatter(const int* __restrict__ ei, int* __restrict__ row_ptr,
                          int* __restrict__ csr_src) {
    int e = blockIdx.x * blockDim.x + threadIdx.x;
    if (e >= E_EDGES) return;
    int src = ei[e], dst = ei[E_EDGES + e];
    int p = atomicAdd(&row_ptr[dst], 1);
    csr_src[p] = src;
}

// ---------------- layer-1 edge phase on RAW x -> y16 (skip-max softmax) ----------------
__global__ void k_edge_l1x(const int* __restrict__ row_ptr, const int* __restrict__ csr_src,
                           const float* __restrict__ x, const float* __restrict__ es,
                           const float* __restrict__ ed, __half* __restrict__ y16) {
    int wid = (blockIdx.x * blockDim.x + threadIdx.x) >> 6;
    int l = threadIdx.x & 63;
    if (wid >= N_NODES) return;
    const int dst = wid;
    const int hh = l >> 4, sub = l & 15;
    const int beg = dst ? row_ptr[dst - 1] : 0;
    const int end = row_ptr[dst];
    const float eddg = ed[dst * 4 + hh];
    const float self_v = lrelu(es[dst * 4 + hh] + eddg);

    float s = 0.f;
    for (int k = beg + sub; k < end; k += 16)
        s += __expf(lrelu(es[csr_src[k] * 4 + hh] + eddg));
    #pragma unroll
    for (int off = 1; off < 16; off <<= 1) s += __shfl_xor(s, off, 64);
    float p_self = __expf(self_v);
    s += p_self;
    float inv_s = 1.f / s;

    float ih[4], eh[4], ph[4];
    #pragma unroll
    for (int h = 0; h < 4; ++h) {
        ih[h] = __shfl(inv_s, h * 16, 64);
        eh[h] = __shfl(eddg, h * 16, 64);
        ph[h] = __shfl(p_self, h * 16, 64);
    }

    const int g = l / 21;
    const int c = l - g * 21;
    const bool act = (l < 63);

    float xdv = (act && g == 0) ? x[(size_t)dst * 21 + c] : 0.f;
    float acc[4];
    #pragma unroll
    for (int h = 0; h < 4; ++h) acc[h] = ph[h] * ih[h] * xdv;

    if (act) {
        int k = beg + g;
        for (; k + 3 < end; k += 6) {
            int s0 = csr_src[k], s1 = csr_src[k + 3];
            float4 e0 = *(const float4*)&es[s0 * 4];
            float4 e1 = *(const float4*)&es[s1 * 4];
            float x0 = x[(size_t)s0 * 21 + c];
            float x1 = x[(size_t)s1 * 21 + c];
            #pragma unroll
            for (int h = 0; h < 4; ++h) {
                float a0 = __expf(lrelu((&e0.x)[h] + eh[h])) * ih[h];
                float a1 = __expf(lrelu((&e1.x)[h] + eh[h])) * ih[h];
                acc[h] += a0 * x0 + a1 * x1;
            }
        }
        if (k < end) {
            int s0 = csr_src[k];
            float4 e0 = *(const float4*)&es[s0 * 4];
            float x0 = x[(size_t)s0 * 21 + c];
            #pragma unroll
            for (int h = 0; h < 4; ++h) {
                float a0 = __expf(lrelu((&e0.x)[h] + eh[h])) * ih[h];
                acc[h] += a0 * x0;
            }
        }
    }

    #pragma unroll
    for (int h = 0; h < 4; ++h) {
        float a1 = __shfl(acc[h], (l + 21) & 63, 64);
        float a2 = __shfl(acc[h], (l + 42) & 63, 64);
        acc[h] += a1 + a2;
    }
    if (l < 32) {
        #pragma unroll
        for (int h = 0; h < 4; ++h) {
            float v = (l < 21) ? acc[h] : 0.f;
            y16[(size_t)dst * 128 + h * 32 + l] = __float2half_rn(v);
        }
    }
}

// ---------------- fused layers 1-post + 2-GEMM via MFMA ----------------
__global__ void k_l12_fused(const __half* __restrict__ y16, const __half* __restrict__ W1t,
                            const float* __restrict__ b1, const __half* __restrict__ W2t,
                            const float* __restrict__ a_src, const float* __restrict__ a_dst,
                            __half* __restrict__ C16, float* __restrict__ es, float* __restrict__ ed) {
    __shared__ _Float16 As[32][520];
    __shared__ float p1s[32][4];
    __shared__ float p2s[32][4];

    const int t = threadIdx.x;
    const int l = t & 63;
    const int wv = t >> 6;
    const int row0 = blockIdx.x * 32;
    const int lr = l & 15;
    const int kg = l >> 4;

    const _Float16* Y = (const _Float16*)y16;
    const _Float16* B1 = (const _Float16*)W1t;

    int ra0 = row0 + lr;       ra0 = ra0 < N_NODES ? ra0 : N_NODES - 1;
    int ra1 = row0 + 16 + lr;  ra1 = ra1 < N_NODES ? ra1 : N_NODES - 1;

    f32x4 acc1[2][8];
    #pragma unroll
    for (int m = 0; m < 2; ++m)
        #pragma unroll
        for (int n = 0; n < 8; ++n) acc1[m][n] = (f32x4){0.f, 0.f, 0.f, 0.f};

    f16x8 a0 = *(const f16x8*)(Y + (size_t)ra0 * 128 + wv * 32 + kg * 8);
    f16x8 a1 = *(const f16x8*)(Y + (size_t)ra1 * 128 + wv * 32 + kg * 8);

    #pragma unroll
    for (int nt = 0; nt < 8; ++nt) {
        f16x8 bf = *(const f16x8*)(B1 + (size_t)(wv * 128 + nt * 16 + lr) * 32 + kg * 8);
        acc1[0][nt] = __builtin_amdgcn_mfma_f32_16x16x32_f16(a0, bf, acc1[0][nt], 0, 0, 0);
        acc1[1][nt] = __builtin_amdgcn_mfma_f32_16x16x32_f16(a1, bf, acc1[1][nt], 0, 0, 0);
    }

    float bb[8];
    #pragma unroll
    for (int nt = 0; nt < 8; ++nt) bb[nt] = b1[wv * 128 + nt * 16 + lr];

    #pragma unroll
    for (int m = 0; m < 2; ++m) {
        #pragma unroll
        for (int r = 0; r < 4; ++r) {
            int rl = m * 16 + kg * 4 + r;
            #pragma unroll
            for (int nt = 0; nt < 8; ++nt) {
                float v = acc1[m][nt][r] + bb[nt];
                v = v > 0.f ? v : __expf(v) - 1.f;
                As[rl][wv * 128 + nt * 16 + lr] = (_Float16)v;
            }
        }
    }
    __syncthreads();

    const _Float16* B2 = (const _Float16*)W2t;
    const int n_g = wv * 16 + lr;
    f32x4 acc2[2];
    acc2[0] = (f32x4){0.f, 0.f, 0.f, 0.f};
    acc2[1] = (f32x4){0.f, 0.f, 0.f, 0.f};

    for (int kb = 0; kb < 512; kb += 32) {
        f16x8 fa0 = *(const f16x8*)&As[lr][kb + kg * 8];
        f16x8 fa1 = *(const f16x8*)&As[16 + lr][kb + kg * 8];
        f16x8 bf = *(const f16x8*)(B2 + (size_t)n_g * 512 + kb + kg * 8);
        acc2[0] = __builtin_amdgcn_mfma_f32_16x16x32_f16(fa0, bf, acc2[0], 0, 0, 0);
        acc2[1] = __builtin_amdgcn_mfma_f32_16x16x32_f16(fa1, bf, acc2[1], 0, 0, 0);
    }

    const float asv = a_src[n_g];
    const float adv = a_dst[n_g];

    #pragma unroll
    for (int m = 0; m < 2; ++m) {
        #pragma unroll
        for (int r = 0; r < 4; ++r) {
            int rl = m * 16 + kg * 4 + r;
            int grow = row0 + rl;
            float cv = acc2[m][r];
            float p1 = cv * asv, p2 = cv * adv;
            #pragma unroll
            for (int off = 1; off < 16; off <<= 1) {
                p1 += __shfl_xor(p1, off, 64);
                p2 += __shfl_xor(p2, off, 64);
            }
            if (grow < N_NODES)
                C16[(size_t)grow * 64 + n_g] = __float2half_rn(cv);
            if (lr == 0) { p1s[rl][wv] = p1; p2s[rl][wv] = p2; }
        }
    }
    __syncthreads();

    if (t < 32) {
        int grow = row0 + t;
        if (grow < N_NODES) {
            es[grow] = p1s[t][0] + p1s[t][1] + p1s[t][2] + p1s[t][3];
            ed[grow] = p2s[t][0] + p2s[t][1] + p2s[t][2] + p2s[t][3];
        }
    }
}

// ---------------- Layer 2 edge phase + fused layer-3 GEMM/coef ----------------
__global__ void k_gat_edge_l2_l3(const int* __restrict__ row_ptr, const int* __restrict__ csr_src,
                                 const __half* __restrict__ h16, const float* __restrict__ es,
                                 const float* __restrict__ ed, const float* __restrict__ b,
                                 const float* __restrict__ W3, const float* __restrict__ a_src3,
                                 const float* __restrict__ a_dst3, float* __restrict__ h3,
                                 float* __restrict__ es3, float* __restrict__ ed3) {
    int wid = (blockIdx.x * blockDim.x + threadIdx.x) >> 6;
    int lane = threadIdx.x & 63;
    if (wid >= N_NODES) return;
    const int dst = wid;
    const int g = lane >> 4, sub = lane & 15;
    const int beg = dst ? row_ptr[dst - 1] : 0;
    const int end = row_ptr[dst];
    const float edd = ed[dst];
    const float self_v = lrelu(es[dst] + edd);

    float s = 0.f;
    for (int k = beg + lane; k < end; k += 64)
        s += __expf(lrelu(es[csr_src[k]] + edd));
    #pragma unroll
    for (int off = 32; off; off >>= 1) s += __shfl_xor(s, off, 64);
    float p_self = __expf(self_v);
    s += p_self;
    const float inv_s = 1.f / s;

    float acc[4] = {0.f, 0.f, 0.f, 0.f};
    if (g == 0) {
        uint2 r = *(const uint2*)(h16 + (size_t)dst * 64 + sub * 4);
        float hv[4]; h4_to_f4(r, hv);
        float a_self = p_self * inv_s;
        #pragma unroll
        for (int j = 0; j < 4; ++j) acc[j] = a_self * hv[j];
    }
    for (int k0 = beg; k0 < end; k0 += 4) {
        int k = k0 + g;
        if (k < end) {
            int src = csr_src[k];
            float alpha = __expf(lrelu(es[src] + edd)) * inv_s;
            uint2 r = *(const uint2*)(h16 + (size_t)src * 64 + sub * 4);
            float hv[4]; h4_to_f4(r, hv);
            #pragma unroll
            for (int j = 0; j < 4; ++j) acc[j] += alpha * hv[j];
        }
    }
    #pragma unroll
    for (int off = 16; off < 64; off <<= 1) {
        #pragma unroll
        for (int j = 0; j < 4; ++j) acc[j] += __shfl_xor(acc[j], off, 64);
    }

    float4 bv = *(const float4*)&b[sub * 4];
    float4 w3 = *(const float4*)&W3[sub * 4];
    float o0 = acc[0] + bv.x, o1 = acc[1] + bv.y, o2 = acc[2] + bv.z, o3 = acc[3] + bv.w;
    o0 = o0 > 0.f ? o0 : expm1f(o0);
    o1 = o1 > 0.f ? o1 : expm1f(o1);
    o2 = o2 > 0.f ? o2 : expm1f(o2);
    o3 = o3 > 0.f ? o3 : expm1f(o3);
    float pp = o0 * w3.x + o1 * w3.y + o2 * w3.z + o3 * w3.w;
    #pragma unroll
    for (int off = 1; off < 16; off <<= 1) pp += __shfl_xor(pp, off, 64);

    if (lane == 0) {
        h3[dst] = pp;
        es3[dst] = pp * a_src3[0];
        ed3[dst] = pp * a_dst3[0];
    }
}

// ---------------- layer 3 edge phase + mean: 16 lanes/dst, grid-stride, 1 atomic/block ----------------
#define MEAN_BLOCKS 200
__global__ void k_gat_edge_c1_mean(const int* __restrict__ row_ptr, const int* __restrict__ csr_src,
                                   const float* __restrict__ h, const float* __restrict__ es,
                                   const float* __restrict__ ed, const float* __restrict__ b3,
                                   float* __restrict__ out) {
    __shared__ float sdata[256];
    const int t = threadIdx.x;
    const int sub = t & 15;
    const int slot = t >> 4;              // 16 dst-slots per block iteration
    const int ntiles = (N_NODES + 15) / 16;
    float local = 0.f;

    for (int tile = blockIdx.x; tile < ntiles; tile += gridDim.x) {
        int dst = tile * 16 + slot;
        if (dst < N_NODES) {
            int beg = dst ? row_ptr[dst - 1] : 0;
            int end = row_ptr[dst];
            float edd = ed[dst];
            float s = 0.f, acc = 0.f;
            for (int k = beg + sub; k < end; k += 16) {
                int src = csr_src[k];
                float pv = __expf(lrelu(es[src] + edd));
                s += pv;
                acc += pv * h[src];
            }
            #pragma unroll
            for (int off = 1; off < 16; off <<= 1) {
                s += __shfl_xor(s, off, 64);
                acc += __shfl_xor(acc, off, 64);
            }
            if (sub == 0) {
                float p = __expf(lrelu(es[dst] + edd));
                s += p;
                acc += p * h[dst];
                local += acc / s;
            }
        }
    }

    sdata[t] = local;
    __syncthreads();
    for (int sft = 128; sft > 0; sft >>= 1) {
        if (t < sft) sdata[t] += sdata[t + sft];
        __syncthreads();
    }
    if (t == 0) {
        float add = sdata[0] / (float)N_NODES;
        if (blockIdx.x == 0) add += b3[0];
        atomicAdd(out, add);
    }
}

extern "C" void kernel_launch(void* const* d_in, const int* in_sizes, int n_in,
                              void* d_out, int out_size, void* d_ws, size_t ws_size,
                              hipStream_t stream) {
    const float* x      = (const float*)d_in[0];
    const float* W1     = (const float*)d_in[1];
    const float* a_src1 = (const float*)d_in[2];
    const float* a_dst1 = (const float*)d_in[3];
    const float* b1     = (const float*)d_in[4];
    const float* W2     = (const float*)d_in[5];
    const float* a_src2 = (const float*)d_in[6];
    const float* a_dst2 = (const float*)d_in[7];
    const float* b2     = (const float*)d_in[8];
    const float* W3     = (const float*)d_in[9];
    const float* a_src3 = (const float*)d_in[10];
    const float* a_dst3 = (const float*)d_in[11];
    const float* b3     = (const float*)d_in[12];
    const int*   ei     = (const int*)d_in[13];
    float* out = (float*)d_out;

    const int BS = 256;
    const size_t N = N_NODES;

    // workspace layout (float units)
    float*  ws      = (float*)d_ws;
    __half* y16     = (__half*)ws;                 // N*128 halves = N*64 floats
    __half* h2_16   = (__half*)(ws + N * 64);      // N*64 halves = N*32 floats
    float*  h3raw   = ws + N * 96;                 // N
    float*  es3     = h3raw + N;                   // N
    float*  ed3     = es3 + N;                     // N
    float*  es_buf  = ed3 + N;                     // N*4
    float*  ed_buf  = es_buf + N * 4;              // N*4
    __half* W1t     = (__half*)(ed_buf + N * 4);   // 512*32 halves = 8192 floats
    __half* W2t     = (__half*)(ed_buf + N * 4 + 8192); // 64*512 halves = 16384 floats
    int*    deg     = (int*)(ed_buf + N * 4 + 8192 + 16384); // N
    int*    row_ptr = deg + N;                     // N (end-pointer convention)
    int*    csr_src = row_ptr + N;                 // E_EDGES
    int*    bsum    = csr_src + E_EDGES;           // 256

    // prep: degree count + layer-1 coef + weight transposes (one kernel)
    hipMemsetAsync(deg, 0, N * sizeof(int), stream);
    k_prep<<<cdiv(E_EDGES, BS), BS, 0, stream>>>(ei, deg, x, W1, a_src1, a_dst1,
                                                 es_buf, ed_buf, W2, W1t, W2t);

    // CSR scan + end-pointer scatter
    k_scan1<<<SCAN_BLOCKS, 256, 0, stream>>>(deg, bsum);
    k_scan2<<<1, 256, 0, stream>>>(bsum);
    k_scan3<<<SCAN_BLOCKS, 256, 0, stream>>>(deg, bsum, row_ptr);
    k_scatter<<<cdiv(E_EDGES, BS), BS, 0, stream>>>(ei, row_ptr, csr_src);

    // Layer 1 edge aggregation on raw x
    k_edge_l1x<<<cdiv((long)N * 64, BS), BS, 0, stream>>>(row_ptr, csr_src, x, es_buf, ed_buf, y16);

    // Fused: out1 = ELU(y@W1+b1) (LDS) then h2 = out1@W2 + es/ed
    k_l12_fused<<<cdiv(N_NODES, 32), 256, 0, stream>>>(y16, W1t, b1, W2t, a_src2, a_dst2, h2_16, es_buf, ed_buf);

    // Layer 2 edge phase with fused layer-3 GEMM + coefficients
    k_gat_edge_l2_l3<<<cdiv((long)N * 64, BS), BS, 0, stream>>>(row_ptr, csr_src, h2_16, es_buf, ed_buf,
                                                                b2, W3, a_src3, a_dst3, h3raw, es3, ed3);

    // Layer 3 edge phase + mean (grid-stride, one atomic per block)
    hipMemsetAsync(out, 0, sizeof(float), stream);
    k_gat_edge_c1_mean<<<MEAN_BLOCKS, 256, 0, stream>>>(row_ptr, csr_src, h3raw, es3, ed3, b3, out);
}

// Round 19
// 167.328 us; speedup vs baseline: 1.1594x; 1.0139x over previous
//
#include <hip/hip_runtime.h>
#include <hip/hip_fp16.h>
#include <math.h>

#define N_NODES 50000
#define E_EDGES 400000
#define NEG_SLOPE 0.2f
#define SCAN_BLOCKS 250
#define SCAN_CHUNK 200

typedef _Float16 f16x8 __attribute__((ext_vector_type(8)));
typedef float f32x4 __attribute__((ext_vector_type(4)));

static inline int cdiv(long a, int b) { return (int)((a + b - 1) / b); }

__device__ __forceinline__ float lrelu(float v) {
    return v > 0.f ? v : NEG_SLOPE * v;
}

__device__ __forceinline__ void h4_to_f4(uint2 u, float o[4]) {
    union { uint2 u2; __half h[4]; } cv;
    cv.u2 = u;
    #pragma unroll
    for (int i = 0; i < 4; ++i) o[i] = __half2float(cv.h[i]);
}

// ---------------- prep: edge-count + layer-1 coef + x->fp16 + weight transposes ----------------
__global__ void k_prep(const int* __restrict__ ei, int* __restrict__ deg,
                       const float* __restrict__ x, const float* __restrict__ W1,
                       const float* __restrict__ a_src, const float* __restrict__ a_dst,
                       float* __restrict__ es, float* __restrict__ ed,
                       const float* __restrict__ W2, __half* __restrict__ W1t,
                       __half* __restrict__ W2t, __half* __restrict__ x16) {
    __shared__ float wesS[88], wedS[88];
    const int t = threadIdx.x;
    const int gid = blockIdx.x * blockDim.x + t;

    if (gid < E_EDGES) atomicAdd(&deg[ei[E_EDGES + gid]], 1);

    if (gid < 512 * 32) {
        int n = gid >> 5, k = gid & 31;
        W1t[gid] = (k < 21) ? __float2half_rn(W1[k * 512 + n]) : __half(0.f);
    } else if (gid < 512 * 32 + 512 * 64) {
        int j = gid - 512 * 32;
        int k = j >> 6, n = j & 63;
        W2t[(size_t)n * 512 + k] = __float2half_rn(W2[j]);
    }

    if (blockIdx.x < (N_NODES + 255) / 256) {
        if (t < 168) {
            int which = t / 84;
            int idx = t % 84;
            int k = idx >> 2, h = idx & 3;
            const float* a = which ? a_dst : a_src;
            float s = 0.f;
            for (int c = 0; c < 128; ++c)
                s += W1[k * 512 + h * 128 + c] * a[h * 128 + c];
            (which ? wedS : wesS)[idx] = s;
        }
        __syncthreads();

        int node = blockIdx.x * blockDim.x + t;
        if (node < N_NODES) {
            const float* xr = x + (size_t)node * 21;
            float e1[4] = {0.f, 0.f, 0.f, 0.f}, e2[4] = {0.f, 0.f, 0.f, 0.f};
            #pragma unroll
            for (int k = 0; k < 21; ++k) {
                float xv = xr[k];
                x16[(size_t)node * 21 + k] = __float2half_rn(xv);
                float4 a = *(const float4*)&wesS[k * 4];
                float4 b = *(const float4*)&wedS[k * 4];
                e1[0] += xv * a.x; e1[1] += xv * a.y; e1[2] += xv * a.z; e1[3] += xv * a.w;
                e2[0] += xv * b.x; e2[1] += xv * b.y; e2[2] += xv * b.z; e2[3] += xv * b.w;
            }
            *(float4*)&es[node * 4] = make_float4(e1[0], e1[1], e1[2], e1[3]);
            *(float4*)&ed[node * 4] = make_float4(e2[0], e2[1], e2[2], e2[3]);
        }
    }
}

// ---------------- CSR scan ----------------
__global__ void k_scan1(const int* __restrict__ deg, int* __restrict__ bsum) {
    __shared__ int sd[256];
    int b = blockIdx.x, t = threadIdx.x;
    int lo = b * SCAN_CHUNK;
    int s = 0;
    for (int i = t; i < SCAN_CHUNK; i += 256) s += deg[lo + i];
    sd[t] = s;
    __syncthreads();
    for (int off = 128; off; off >>= 1) {
        if (t < off) sd[t] += sd[t + off];
        __syncthreads();
    }
    if (t == 0) bsum[b] = sd[0];
}

// merged scan2+scan3: each block computes its own base from raw bsum, then local scan
__global__ void k_scan23(const int* __restrict__ deg, const int* __restrict__ bsum,
                         int* __restrict__ row_ptr) {
    __shared__ int sd[256];
    __shared__ int base_s;
    int b = blockIdx.x, t = threadIdx.x;

    // base = sum of bsum[0..b)
    int v = (t < b) ? bsum[t] : 0;
    sd[t] = v;
    __syncthreads();
    for (int off = 128; off; off >>= 1) {
        if (t < off) sd[t] += sd[t + off];
        __syncthreads();
    }
    if (t == 0) base_s = sd[0];
    __syncthreads();
    const int base = base_s;
    __syncthreads();

    // local exclusive scan of deg chunk
    int lo = b * SCAN_CHUNK;
    int dv = (t < SCAN_CHUNK) ? deg[lo + t] : 0;
    sd[t] = dv;
    __syncthreads();
    for (int off = 1; off < 256; off <<= 1) {
        int u = (t >= off) ? sd[t - off] : 0;
        __syncthreads();
        sd[t] += u;
        __syncthreads();
    }
    if (t < SCAN_CHUNK) row_ptr[lo + t] = base + sd[t] - dv;
}

// end-pointer scatter: atomicAdd on row_ptr itself; afterwards row_ptr[d] = segment end.
__global__ void k_scatter(const int* __restrict__ ei, int* __restrict__ row_ptr,
                          int* __restrict__ csr_src) {
    int e = blockIdx.x * blockDim.x + threadIdx.x;
    if (e >= E_EDGES) return;
    int src = ei[e], dst = ei[E_EDGES + e];
    int p = atomicAdd(&row_ptr[dst], 1);
    csr_src[p] = src;
}

// ---------------- layer-1 edge phase on fp16 x -> y16 (skip-max softmax) ----------------
__global__ void k_edge_l1x(const int* __restrict__ row_ptr, const int* __restrict__ csr_src,
                           const __half* __restrict__ x16, const float* __restrict__ es,
                           const float* __restrict__ ed, __half* __restrict__ y16) {
    int wid = (blockIdx.x * blockDim.x + threadIdx.x) >> 6;
    int l = threadIdx.x & 63;
    if (wid >= N_NODES) return;
    const int dst = wid;
    const int hh = l >> 4, sub = l & 15;
    const int beg = dst ? row_ptr[dst - 1] : 0;
    const int end = row_ptr[dst];
    const float eddg = ed[dst * 4 + hh];
    const float self_v = lrelu(es[dst * 4 + hh] + eddg);

    float s = 0.f;
    for (int k = beg + sub; k < end; k += 16)
        s += __expf(lrelu(es[csr_src[k] * 4 + hh] + eddg));
    #pragma unroll
    for (int off = 1; off < 16; off <<= 1) s += __shfl_xor(s, off, 64);
    float p_self = __expf(self_v);
    s += p_self;
    float inv_s = 1.f / s;

    float ih[4], eh[4], ph[4];
    #pragma unroll
    for (int h = 0; h < 4; ++h) {
        ih[h] = __shfl(inv_s, h * 16, 64);
        eh[h] = __shfl(eddg, h * 16, 64);
        ph[h] = __shfl(p_self, h * 16, 64);
    }

    const int g = l / 21;
    const int c = l - g * 21;
    const bool act = (l < 63);

    float xdv = (act && g == 0) ? __half2float(x16[(size_t)dst * 21 + c]) : 0.f;
    float acc[4];
    #pragma unroll
    for (int h = 0; h < 4; ++h) acc[h] = ph[h] * ih[h] * xdv;

    if (act) {
        int k = beg + g;
        for (; k + 3 < end; k += 6) {
            int s0 = csr_src[k], s1 = csr_src[k + 3];
            float4 e0 = *(const float4*)&es[s0 * 4];
            float4 e1 = *(const float4*)&es[s1 * 4];
            float x0 = __half2float(x16[(size_t)s0 * 21 + c]);
            float x1 = __half2float(x16[(size_t)s1 * 21 + c]);
            #pragma unroll
            for (int h = 0; h < 4; ++h) {
                float a0 = __expf(lrelu((&e0.x)[h] + eh[h])) * ih[h];
                float a1 = __expf(lrelu((&e1.x)[h] + eh[h])) * ih[h];
                acc[h] += a0 * x0 + a1 * x1;
            }
        }
        if (k < end) {
            int s0 = csr_src[k];
            float4 e0 = *(const float4*)&es[s0 * 4];
            float x0 = __half2float(x16[(size_t)s0 * 21 + c]);
            #pragma unroll
            for (int h = 0; h < 4; ++h) {
                float a0 = __expf(lrelu((&e0.x)[h] + eh[h])) * ih[h];
                acc[h] += a0 * x0;
            }
        }
    }

    #pragma unroll
    for (int h = 0; h < 4; ++h) {
        float a1 = __shfl(acc[h], (l + 21) & 63, 64);
        float a2 = __shfl(acc[h], (l + 42) & 63, 64);
        acc[h] += a1 + a2;
    }
    if (l < 32) {
        #pragma unroll
        for (int h = 0; h < 4; ++h) {
            float v = (l < 21) ? acc[h] : 0.f;
            y16[(size_t)dst * 128 + h * 32 + l] = __float2half_rn(v);
        }
    }
}

// ---------------- fused layers 1-post + 2-GEMM via MFMA ----------------
__global__ void k_l12_fused(const __half* __restrict__ y16, const __half* __restrict__ W1t,
                            const float* __restrict__ b1, const __half* __restrict__ W2t,
                            const float* __restrict__ a_src, const float* __restrict__ a_dst,
                            __half* __restrict__ C16, float* __restrict__ es, float* __restrict__ ed) {
    __shared__ _Float16 As[32][520];
    __shared__ float p1s[32][4];
    __shared__ float p2s[32][4];

    const int t = threadIdx.x;
    const int l = t & 63;
    const int wv = t >> 6;
    const int row0 = blockIdx.x * 32;
    const int lr = l & 15;
    const int kg = l >> 4;

    const _Float16* Y = (const _Float16*)y16;
    const _Float16* B1 = (const _Float16*)W1t;

    int ra0 = row0 + lr;       ra0 = ra0 < N_NODES ? ra0 : N_NODES - 1;
    int ra1 = row0 + 16 + lr;  ra1 = ra1 < N_NODES ? ra1 : N_NODES - 1;

    f32x4 acc1[2][8];
    #pragma unroll
    for (int m = 0; m < 2; ++m)
        #pragma unroll
        for (int n = 0; n < 8; ++n) acc1[m][n] = (f32x4){0.f, 0.f, 0.f, 0.f};

    f16x8 a0 = *(const f16x8*)(Y + (size_t)ra0 * 128 + wv * 32 + kg * 8);
    f16x8 a1 = *(const f16x8*)(Y + (size_t)ra1 * 128 + wv * 32 + kg * 8);

    #pragma unroll
    for (int nt = 0; nt < 8; ++nt) {
        f16x8 bf = *(const f16x8*)(B1 + (size_t)(wv * 128 + nt * 16 + lr) * 32 + kg * 8);
        acc1[0][nt] = __builtin_amdgcn_mfma_f32_16x16x32_f16(a0, bf, acc1[0][nt], 0, 0, 0);
        acc1[1][nt] = __builtin_amdgcn_mfma_f32_16x16x32_f16(a1, bf, acc1[1][nt], 0, 0, 0);
    }

    float bb[8];
    #pragma unroll
    for (int nt = 0; nt < 8; ++nt) bb[nt] = b1[wv * 128 + nt * 16 + lr];

    #pragma unroll
    for (int m = 0; m < 2; ++m) {
        #pragma unroll
        for (int r = 0; r < 4; ++r) {
            int rl = m * 16 + kg * 4 + r;
            #pragma unroll
            for (int nt = 0; nt < 8; ++nt) {
                float v = acc1[m][nt][r] + bb[nt];
                v = v > 0.f ? v : __expf(v) - 1.f;
                As[rl][wv * 128 + nt * 16 + lr] = (_Float16)v;
            }
        }
    }
    __syncthreads();

    const _Float16* B2 = (const _Float16*)W2t;
    const int n_g = wv * 16 + lr;
    f32x4 acc2[2];
    acc2[0] = (f32x4){0.f, 0.f, 0.f, 0.f};
    acc2[1] = (f32x4){0.f, 0.f, 0.f, 0.f};

    for (int kb = 0; kb < 512; kb += 32) {
        f16x8 fa0 = *(const f16x8*)&As[lr][kb + kg * 8];
        f16x8 fa1 = *(const f16x8*)&As[16 + lr][kb + kg * 8];
        f16x8 bf = *(const f16x8*)(B2 + (size_t)n_g * 512 + kb + kg * 8);
        acc2[0] = __builtin_amdgcn_mfma_f32_16x16x32_f16(fa0, bf, acc2[0], 0, 0, 0);
        acc2[1] = __builtin_amdgcn_mfma_f32_16x16x32_f16(fa1, bf, acc2[1], 0, 0, 0);
    }

    const float asv = a_src[n_g];
    const float adv = a_dst[n_g];

    #pragma unroll
    for (int m = 0; m < 2; ++m) {
        #pragma unroll
        for (int r = 0; r < 4; ++r) {
            int rl = m * 16 + kg * 4 + r;
            int grow = row0 + rl;
            float cv = acc2[m][r];
            float p1 = cv * asv, p2 = cv * adv;
            #pragma unroll
            for (int off = 1; off < 16; off <<= 1) {
                p1 += __shfl_xor(p1, off, 64);
                p2 += __shfl_xor(p2, off, 64);
            }
            if (grow < N_NODES)
                C16[(size_t)grow * 64 + n_g] = __float2half_rn(cv);
            if (lr == 0) { p1s[rl][wv] = p1; p2s[rl][wv] = p2; }
        }
    }
    __syncthreads();

    if (t < 32) {
        int grow = row0 + t;
        if (grow < N_NODES) {
            es[grow] = p1s[t][0] + p1s[t][1] + p1s[t][2] + p1s[t][3];
            ed[grow] = p2s[t][0] + p2s[t][1] + p2s[t][2] + p2s[t][3];
        }
    }
}

// ---------------- Layer 2 edge phase + fused layer-3 GEMM/coef ----------------
__global__ void k_gat_edge_l2_l3(const int* __restrict__ row_ptr, const int* __restrict__ csr_src,
                                 const __half* __restrict__ h16, const float* __restrict__ es,
                                 const float* __restrict__ ed, const float* __restrict__ b,
                                 const float* __restrict__ W3, const float* __restrict__ a_src3,
                                 const float* __restrict__ a_dst3, float* __restrict__ h3,
                                 float* __restrict__ es3, float* __restrict__ ed3) {
    int wid = (blockIdx.x * blockDim.x + threadIdx.x) >> 6;
    int lane = threadIdx.x & 63;
    if (wid >= N_NODES) return;
    const int dst = wid;
    const int g = lane >> 4, sub = lane & 15;
    const int beg = dst ? row_ptr[dst - 1] : 0;
    const int end = row_ptr[dst];
    const float edd = ed[dst];
    const float self_v = lrelu(es[dst] + edd);

    float s = 0.f;
    for (int k = beg + lane; k < end; k += 64)
        s += __expf(lrelu(es[csr_src[k]] + edd));
    #pragma unroll
    for (int off = 32; off; off >>= 1) s += __shfl_xor(s, off, 64);
    float p_self = __expf(self_v);
    s += p_self;
    const float inv_s = 1.f / s;

    float acc[4] = {0.f, 0.f, 0.f, 0.f};
    if (g == 0) {
        uint2 r = *(const uint2*)(h16 + (size_t)dst * 64 + sub * 4);
        float hv[4]; h4_to_f4(r, hv);
        float a_self = p_self * inv_s;
        #pragma unroll
        for (int j = 0; j < 4; ++j) acc[j] = a_self * hv[j];
    }
    for (int k0 = beg; k0 < end; k0 += 4) {
        int k = k0 + g;
        if (k < end) {
            int src = csr_src[k];
            float alpha = __expf(lrelu(es[src] + edd)) * inv_s;
            uint2 r = *(const uint2*)(h16 + (size_t)src * 64 + sub * 4);
            float hv[4]; h4_to_f4(r, hv);
            #pragma unroll
            for (int j = 0; j < 4; ++j) acc[j] += alpha * hv[j];
        }
    }
    #pragma unroll
    for (int off = 16; off < 64; off <<= 1) {
        #pragma unroll
        for (int j = 0; j < 4; ++j) acc[j] += __shfl_xor(acc[j], off, 64);
    }

    float4 bv = *(const float4*)&b[sub * 4];
    float4 w3 = *(const float4*)&W3[sub * 4];
    float o0 = acc[0] + bv.x, o1 = acc[1] + bv.y, o2 = acc[2] + bv.z, o3 = acc[3] + bv.w;
    o0 = o0 > 0.f ? o0 : expm1f(o0);
    o1 = o1 > 0.f ? o1 : expm1f(o1);
    o2 = o2 > 0.f ? o2 : expm1f(o2);
    o3 = o3 > 0.f ? o3 : expm1f(o3);
    float pp = o0 * w3.x + o1 * w3.y + o2 * w3.z + o3 * w3.w;
    #pragma unroll
    for (int off = 1; off < 16; off <<= 1) pp += __shfl_xor(pp, off, 64);

    if (lane == 0) {
        h3[dst] = pp;
        es3[dst] = pp * a_src3[0];
        ed3[dst] = pp * a_dst3[0];
    }
}

// ---------------- layer 3 edge phase + mean: 16 lanes/dst, grid-stride, 1 atomic/block ----------------
#define MEAN_BLOCKS 200
__global__ void k_gat_edge_c1_mean(const int* __restrict__ row_ptr, const int* __restrict__ csr_src,
                                   const float* __restrict__ h, const float* __restrict__ es,
                                   const float* __restrict__ ed, const float* __restrict__ b3,
                                   float* __restrict__ out) {
    __shared__ float sdata[256];
    const int t = threadIdx.x;
    const int sub = t & 15;
    const int slot = t >> 4;
    const int ntiles = (N_NODES + 15) / 16;
    float local = 0.f;

    for (int tile = blockIdx.x; tile < ntiles; tile += gridDim.x) {
        int dst = tile * 16 + slot;
        if (dst < N_NODES) {
            int beg = dst ? row_ptr[dst - 1] : 0;
            int end = row_ptr[dst];
            float edd = ed[dst];
            float s = 0.f, acc = 0.f;
            for (int k = beg + sub; k < end; k += 16) {
                int src = csr_src[k];
                float pv = __expf(lrelu(es[src] + edd));
                s += pv;
                acc += pv * h[src];
            }
            #pragma unroll
            for (int off = 1; off < 16; off <<= 1) {
                s += __shfl_xor(s, off, 64);
                acc += __shfl_xor(acc, off, 64);
            }
            if (sub == 0) {
                float p = __expf(lrelu(es[dst] + edd));
                s += p;
                acc += p * h[dst];
                local += acc / s;
            }
        }
    }

    sdata[t] = local;
    __syncthreads();
    for (int sft = 128; sft > 0; sft >>= 1) {
        if (t < sft) sdata[t] += sdata[t + sft];
        __syncthreads();
    }
    if (t == 0) {
        float add = sdata[0] / (float)N_NODES;
        if (blockIdx.x == 0) add += b3[0];
        atomicAdd(out, add);
    }
}

extern "C" void kernel_launch(void* const* d_in, const int* in_sizes, int n_in,
                              void* d_out, int out_size, void* d_ws, size_t ws_size,
                              hipStream_t stream) {
    const float* x      = (const float*)d_in[0];
    const float* W1     = (const float*)d_in[1];
    const float* a_src1 = (const float*)d_in[2];
    const float* a_dst1 = (const float*)d_in[3];
    const float* b1     = (const float*)d_in[4];
    const float* W2     = (const float*)d_in[5];
    const float* a_src2 = (const float*)d_in[6];
    const float* a_dst2 = (const float*)d_in[7];
    const float* b2     = (const float*)d_in[8];
    const float* W3     = (const float*)d_in[9];
    const float* a_src3 = (const float*)d_in[10];
    const float* a_dst3 = (const float*)d_in[11];
    const float* b3     = (const float*)d_in[12];
    const int*   ei     = (const int*)d_in[13];
    float* out = (float*)d_out;

    const int BS = 256;
    const size_t N = N_NODES;

    // workspace layout (float units)
    float*  ws      = (float*)d_ws;
    __half* y16     = (__half*)ws;                 // N*128 halves = N*64 floats
    __half* h2_16   = (__half*)(ws + N * 64);      // N*64 halves = N*32 floats
    float*  h3raw   = ws + N * 96;                 // N
    float*  es3     = h3raw + N;                   // N
    float*  ed3     = es3 + N;                     // N
    float*  es_buf  = ed3 + N;                     // N*4
    float*  ed_buf  = es_buf + N * 4;              // N*4
    __half* W1t     = (__half*)(ed_buf + N * 4);   // 512*32 halves = 8192 floats
    __half* W2t     = (__half*)(ed_buf + N * 4 + 8192); // 64*512 halves = 16384 floats
    __half* x16     = (__half*)(ed_buf + N * 4 + 8192 + 16384); // N*21 halves -> pad to N*11 floats
    int*    deg     = (int*)(ed_buf + N * 4 + 8192 + 16384 + N * 11); // N
    int*    row_ptr = deg + N;                     // N (end-pointer convention)
    int*    csr_src = row_ptr + N;                 // E_EDGES
    int*    bsum    = csr_src + E_EDGES;           // 256

    // prep: degree count + layer-1 coef + x->fp16 + weight transposes
    hipMemsetAsync(deg, 0, N * sizeof(int), stream);
    k_prep<<<cdiv(E_EDGES, BS), BS, 0, stream>>>(ei, deg, x, W1, a_src1, a_dst1,
                                                 es_buf, ed_buf, W2, W1t, W2t, x16);

    // CSR scan (2 dispatches) + end-pointer scatter
    k_scan1<<<SCAN_BLOCKS, 256, 0, stream>>>(deg, bsum);
    k_scan23<<<SCAN_BLOCKS, 256, 0, stream>>>(deg, bsum, row_ptr);
    k_scatter<<<cdiv(E_EDGES, BS), BS, 0, stream>>>(ei, row_ptr, csr_src);

    // Layer 1 edge aggregation on fp16 x
    k_edge_l1x<<<cdiv((long)N * 64, BS), BS, 0, stream>>>(row_ptr, csr_src, x16, es_buf, ed_buf, y16);

    // Fused: out1 = ELU(y@W1+b1) (LDS) then h2 = out1@W2 + es/ed
    k_l12_fused<<<cdiv(N_NODES, 32), 256, 0, stream>>>(y16, W1t, b1, W2t, a_src2, a_dst2, h2_16, es_buf, ed_buf);

    // Layer 2 edge phase with fused layer-3 GEMM + coefficients
    k_gat_edge_l2_l3<<<cdiv((long)N * 64, BS), BS, 0, stream>>>(row_ptr, csr_src, h2_16, es_buf, ed_buf,
                                                                b2, W3, a_src3, a_dst3, h3raw, es3, ed3);

    // Layer 3 edge phase + mean
    hipMemsetAsync(out, 0, sizeof(float), stream);
    k_gat_edge_c1_mean<<<MEAN_BLOCKS, 256, 0, stream>>>(row_ptr, csr_src, h3raw, es3, ed3, b3, out);
}

// Round 20
// 160.880 us; speedup vs baseline: 1.2059x; 1.0401x over previous
//
#include <hip/hip_runtime.h>
#include <hip/hip_fp16.h>
#include <math.h>

#define N_NODES 50000
#define E_EDGES 400000
#define NEG_SLOPE 0.2f
#define SCAN_BLOCKS 250
#define SCAN_CHUNK 200

typedef _Float16 f16x8 __attribute__((ext_vector_type(8)));
typedef float f32x4 __attribute__((ext_vector_type(4)));

static inline int cdiv(long a, int b) { return (int)((a + b - 1) / b); }

__device__ __forceinline__ float lrelu(float v) {
    return v > 0.f ? v : NEG_SLOPE * v;
}

__device__ __forceinline__ void h4_to_f4(uint2 u, float o[4]) {
    union { uint2 u2; __half h[4]; } cv;
    cv.u2 = u;
    #pragma unroll
    for (int i = 0; i < 4; ++i) o[i] = __half2float(cv.h[i]);
}

// ---------------- prep: edge-count + layer-1 coef + x->fp16 + weight transposes ----------------
__global__ void k_prep(const int* __restrict__ ei, int* __restrict__ deg,
                       const float* __restrict__ x, const float* __restrict__ W1,
                       const float* __restrict__ a_src, const float* __restrict__ a_dst,
                       float* __restrict__ es, float* __restrict__ ed,
                       const float* __restrict__ W2, __half* __restrict__ W1t,
                       __half* __restrict__ W2t, __half* __restrict__ x16) {
    __shared__ float wesS[88], wedS[88];
    const int t = threadIdx.x;
    const int gid = blockIdx.x * blockDim.x + t;

    if (gid < E_EDGES) atomicAdd(&deg[ei[E_EDGES + gid]], 1);

    if (gid < 512 * 32) {
        int n = gid >> 5, k = gid & 31;
        W1t[gid] = (k < 21) ? __float2half_rn(W1[k * 512 + n]) : __half(0.f);
    } else if (gid < 512 * 32 + 512 * 64) {
        int j = gid - 512 * 32;
        int k = j >> 6, n = j & 63;
        W2t[(size_t)n * 512 + k] = __float2half_rn(W2[j]);
    }

    if (blockIdx.x < (N_NODES + 255) / 256) {
        if (t < 168) {
            int which = t / 84;
            int idx = t % 84;
            int k = idx >> 2, h = idx & 3;
            const float* a = which ? a_dst : a_src;
            float s = 0.f;
            for (int c = 0; c < 128; ++c)
                s += W1[k * 512 + h * 128 + c] * a[h * 128 + c];
            (which ? wedS : wesS)[idx] = s;
        }
        __syncthreads();

        int node = blockIdx.x * blockDim.x + t;
        if (node < N_NODES) {
            const float* xr = x + (size_t)node * 21;
            float e1[4] = {0.f, 0.f, 0.f, 0.f}, e2[4] = {0.f, 0.f, 0.f, 0.f};
            #pragma unroll
            for (int k = 0; k < 21; ++k) {
                float xv = xr[k];
                x16[(size_t)node * 21 + k] = __float2half_rn(xv);
                float4 a = *(const float4*)&wesS[k * 4];
                float4 b = *(const float4*)&wedS[k * 4];
                e1[0] += xv * a.x; e1[1] += xv * a.y; e1[2] += xv * a.z; e1[3] += xv * a.w;
                e2[0] += xv * b.x; e2[1] += xv * b.y; e2[2] += xv * b.z; e2[3] += xv * b.w;
            }
            *(float4*)&es[node * 4] = make_float4(e1[0], e1[1], e1[2], e1[3]);
            *(float4*)&ed[node * 4] = make_float4(e2[0], e2[1], e2[2], e2[3]);
        }
    }
}

// ---------------- CSR scan ----------------
__global__ void k_scan1(const int* __restrict__ deg, int* __restrict__ bsum) {
    __shared__ int sd[256];
    int b = blockIdx.x, t = threadIdx.x;
    int lo = b * SCAN_CHUNK;
    int s = 0;
    for (int i = t; i < SCAN_CHUNK; i += 256) s += deg[lo + i];
    sd[t] = s;
    __syncthreads();
    for (int off = 128; off; off >>= 1) {
        if (t < off) sd[t] += sd[t + off];
        __syncthreads();
    }
    if (t == 0) bsum[b] = sd[0];
}

__global__ void k_scan23(const int* __restrict__ deg, const int* __restrict__ bsum,
                         int* __restrict__ row_ptr) {
    __shared__ int sd[256];
    __shared__ int base_s;
    int b = blockIdx.x, t = threadIdx.x;

    int v = (t < b) ? bsum[t] : 0;
    sd[t] = v;
    __syncthreads();
    for (int off = 128; off; off >>= 1) {
        if (t < off) sd[t] += sd[t + off];
        __syncthreads();
    }
    if (t == 0) base_s = sd[0];
    __syncthreads();
    const int base = base_s;
    __syncthreads();

    int lo = b * SCAN_CHUNK;
    int dv = (t < SCAN_CHUNK) ? deg[lo + t] : 0;
    sd[t] = dv;
    __syncthreads();
    for (int off = 1; off < 256; off <<= 1) {
        int u = (t >= off) ? sd[t - off] : 0;
        __syncthreads();
        sd[t] += u;
        __syncthreads();
    }
    if (t < SCAN_CHUNK) row_ptr[lo + t] = base + sd[t] - dv;
}

__global__ void k_scatter(const int* __restrict__ ei, int* __restrict__ row_ptr,
                          int* __restrict__ csr_src) {
    int e = blockIdx.x * blockDim.x + threadIdx.x;
    if (e >= E_EDGES) return;
    int src = ei[e], dst = ei[E_EDGES + e];
    int p = atomicAdd(&row_ptr[dst], 1);
    csr_src[p] = src;
}

// ---------------- layer-1 edge phase: SINGLE-PASS unnormalized softmax + aggregate ----------------
// lane l<63: group g=l/21 walks edges beg+g, beg+g+3,...; channel c=l-21g.
// acc[h] = sum exp(v_h)*x[src][c]; ssum[h] accumulated on c==0 lanes; normalize at end.
__global__ void k_edge_l1x(const int* __restrict__ row_ptr, const int* __restrict__ csr_src,
                           const __half* __restrict__ x16, const float* __restrict__ es,
                           const float* __restrict__ ed, __half* __restrict__ y16) {
    int wid = (blockIdx.x * blockDim.x + threadIdx.x) >> 6;
    int l = threadIdx.x & 63;
    if (wid >= N_NODES) return;
    const int dst = wid;
    const int beg = dst ? row_ptr[dst - 1] : 0;
    const int end = row_ptr[dst];

    // per-head dst stats on every lane
    float4 es_d = *(const float4*)&es[dst * 4];
    float4 ed_d = *(const float4*)&ed[dst * 4];
    float eh[4], ph[4];
    #pragma unroll
    for (int h = 0; h < 4; ++h) {
        eh[h] = (&ed_d.x)[h];
        ph[h] = __expf(lrelu((&es_d.x)[h] + eh[h]));
    }

    const int g = l / 21;             // lane 63 -> g=3 (inactive)
    const int c = l - g * 21;
    const bool act = (l < 63);
    const bool lead = act && (c == 0);

    float acc[4] = {0.f, 0.f, 0.f, 0.f};
    float ssum[4] = {0.f, 0.f, 0.f, 0.f};

    if (act) {
        int k = beg + g;
        for (; k + 3 < end; k += 6) {
            int s0 = csr_src[k], s1 = csr_src[k + 3];
            float4 e0 = *(const float4*)&es[s0 * 4];
            float4 e1 = *(const float4*)&es[s1 * 4];
            float x0 = __half2float(x16[(size_t)s0 * 21 + c]);
            float x1 = __half2float(x16[(size_t)s1 * 21 + c]);
            #pragma unroll
            for (int h = 0; h < 4; ++h) {
                float a0 = __expf(lrelu((&e0.x)[h] + eh[h]));
                float a1 = __expf(lrelu((&e1.x)[h] + eh[h]));
                acc[h] += a0 * x0 + a1 * x1;
                if (lead) ssum[h] += a0 + a1;
            }
        }
        if (k < end) {
            int s0 = csr_src[k];
            float4 e0 = *(const float4*)&es[s0 * 4];
            float x0 = __half2float(x16[(size_t)s0 * 21 + c]);
            #pragma unroll
            for (int h = 0; h < 4; ++h) {
                float a0 = __expf(lrelu((&e0.x)[h] + eh[h]));
                acc[h] += a0 * x0;
                if (lead) ssum[h] += a0;
            }
        }
    }

    // 3-way reduce acc and ssum across edge-groups (lanes l<21 get acc totals; lane 0 gets ssum total)
    #pragma unroll
    for (int h = 0; h < 4; ++h) {
        acc[h] += __shfl(acc[h], (l + 21) & 63, 64) + __shfl(acc[h], (l + 42) & 63, 64);
        ssum[h] += __shfl(ssum[h], (l + 21) & 63, 64) + __shfl(ssum[h], (l + 42) & 63, 64);
    }
    float inv[4];
    #pragma unroll
    for (int h = 0; h < 4; ++h) {
        float st = __shfl(ssum[h], 0, 64) + ph[h];
        inv[h] = 1.f / st;
    }

    if (l < 32) {
        float xd = (l < 21) ? __half2float(x16[(size_t)dst * 21 + l]) : 0.f;
        #pragma unroll
        for (int h = 0; h < 4; ++h) {
            float v = (l < 21) ? (acc[h] + ph[h] * xd) * inv[h] : 0.f;
            y16[(size_t)dst * 128 + h * 32 + l] = __float2half_rn(v);
        }
    }
}

// ---------------- fused layers 1-post + 2-GEMM via MFMA ----------------
__global__ void k_l12_fused(const __half* __restrict__ y16, const __half* __restrict__ W1t,
                            const float* __restrict__ b1, const __half* __restrict__ W2t,
                            const float* __restrict__ a_src, const float* __restrict__ a_dst,
                            __half* __restrict__ C16, float* __restrict__ es, float* __restrict__ ed) {
    __shared__ _Float16 As[32][520];
    __shared__ float p1s[32][4];
    __shared__ float p2s[32][4];

    const int t = threadIdx.x;
    const int l = t & 63;
    const int wv = t >> 6;
    const int row0 = blockIdx.x * 32;
    const int lr = l & 15;
    const int kg = l >> 4;

    const _Float16* Y = (const _Float16*)y16;
    const _Float16* B1 = (const _Float16*)W1t;

    int ra0 = row0 + lr;       ra0 = ra0 < N_NODES ? ra0 : N_NODES - 1;
    int ra1 = row0 + 16 + lr;  ra1 = ra1 < N_NODES ? ra1 : N_NODES - 1;

    f32x4 acc1[2][8];
    #pragma unroll
    for (int m = 0; m < 2; ++m)
        #pragma unroll
        for (int n = 0; n < 8; ++n) acc1[m][n] = (f32x4){0.f, 0.f, 0.f, 0.f};

    f16x8 a0 = *(const f16x8*)(Y + (size_t)ra0 * 128 + wv * 32 + kg * 8);
    f16x8 a1 = *(const f16x8*)(Y + (size_t)ra1 * 128 + wv * 32 + kg * 8);

    #pragma unroll
    for (int nt = 0; nt < 8; ++nt) {
        f16x8 bf = *(const f16x8*)(B1 + (size_t)(wv * 128 + nt * 16 + lr) * 32 + kg * 8);
        acc1[0][nt] = __builtin_amdgcn_mfma_f32_16x16x32_f16(a0, bf, acc1[0][nt], 0, 0, 0);
        acc1[1][nt] = __builtin_amdgcn_mfma_f32_16x16x32_f16(a1, bf, acc1[1][nt], 0, 0, 0);
    }

    float bb[8];
    #pragma unroll
    for (int nt = 0; nt < 8; ++nt) bb[nt] = b1[wv * 128 + nt * 16 + lr];

    #pragma unroll
    for (int m = 0; m < 2; ++m) {
        #pragma unroll
        for (int r = 0; r < 4; ++r) {
            int rl = m * 16 + kg * 4 + r;
            #pragma unroll
            for (int nt = 0; nt < 8; ++nt) {
                float v = acc1[m][nt][r] + bb[nt];
                v = v > 0.f ? v : __expf(v) - 1.f;
                As[rl][wv * 128 + nt * 16 + lr] = (_Float16)v;
            }
        }
    }
    __syncthreads();

    const _Float16* B2 = (const _Float16*)W2t;
    const int n_g = wv * 16 + lr;
    f32x4 acc2[2];
    acc2[0] = (f32x4){0.f, 0.f, 0.f, 0.f};
    acc2[1] = (f32x4){0.f, 0.f, 0.f, 0.f};

    for (int kb = 0; kb < 512; kb += 32) {
        f16x8 fa0 = *(const f16x8*)&As[lr][kb + kg * 8];
        f16x8 fa1 = *(const f16x8*)&As[16 + lr][kb + kg * 8];
        f16x8 bf = *(const f16x8*)(B2 + (size_t)n_g * 512 + kb + kg * 8);
        acc2[0] = __builtin_amdgcn_mfma_f32_16x16x32_f16(fa0, bf, acc2[0], 0, 0, 0);
        acc2[1] = __builtin_amdgcn_mfma_f32_16x16x32_f16(fa1, bf, acc2[1], 0, 0, 0);
    }

    const float asv = a_src[n_g];
    const float adv = a_dst[n_g];

    #pragma unroll
    for (int m = 0; m < 2; ++m) {
        #pragma unroll
        for (int r = 0; r < 4; ++r) {
            int rl = m * 16 + kg * 4 + r;
            int grow = row0 + rl;
            float cv = acc2[m][r];
            float p1 = cv * asv, p2 = cv * adv;
            #pragma unroll
            for (int off = 1; off < 16; off <<= 1) {
                p1 += __shfl_xor(p1, off, 64);
                p2 += __shfl_xor(p2, off, 64);
            }
            if (grow < N_NODES)
                C16[(size_t)grow * 64 + n_g] = __float2half_rn(cv);
            if (lr == 0) { p1s[rl][wv] = p1; p2s[rl][wv] = p2; }
        }
    }
    __syncthreads();

    if (t < 32) {
        int grow = row0 + t;
        if (grow < N_NODES) {
            es[grow] = p1s[t][0] + p1s[t][1] + p1s[t][2] + p1s[t][3];
            ed[grow] = p2s[t][0] + p2s[t][1] + p2s[t][2] + p2s[t][3];
        }
    }
}

// ---------------- Layer 2 edge phase + fused layer-3 GEMM/coef: SINGLE-PASS ----------------
// 4 edge-groups x 16 channels; unnormalized acc + ssum (sub==0 lanes); normalize in epilogue.
__global__ void k_gat_edge_l2_l3(const int* __restrict__ row_ptr, const int* __restrict__ csr_src,
                                 const __half* __restrict__ h16, const float* __restrict__ es,
                                 const float* __restrict__ ed, const float* __restrict__ b,
                                 const float* __restrict__ W3, const float* __restrict__ a_src3,
                                 const float* __restrict__ a_dst3, float* __restrict__ h3,
                                 float* __restrict__ es3, float* __restrict__ ed3) {
    int wid = (blockIdx.x * blockDim.x + threadIdx.x) >> 6;
    int lane = threadIdx.x & 63;
    if (wid >= N_NODES) return;
    const int dst = wid;
    const int g = lane >> 4, sub = lane & 15;
    const int beg = dst ? row_ptr[dst - 1] : 0;
    const int end = row_ptr[dst];
    const float edd = ed[dst];
    const float p_self = __expf(lrelu(es[dst] + edd));

    float acc[4] = {0.f, 0.f, 0.f, 0.f};
    float ssum = 0.f;
    for (int k0 = beg; k0 < end; k0 += 4) {
        int k = k0 + g;
        if (k < end) {
            int src = csr_src[k];
            float au = __expf(lrelu(es[src] + edd));   // unnormalized
            uint2 r = *(const uint2*)(h16 + (size_t)src * 64 + sub * 4);
            float hv[4]; h4_to_f4(r, hv);
            #pragma unroll
            for (int j = 0; j < 4; ++j) acc[j] += au * hv[j];
            if (sub == 0) ssum += au;
        }
    }
    #pragma unroll
    for (int off = 16; off < 64; off <<= 1) {
        #pragma unroll
        for (int j = 0; j < 4; ++j) acc[j] += __shfl_xor(acc[j], off, 64);
        ssum += __shfl_xor(ssum, off, 64);
    }
    const float inv_s = 1.f / (__shfl(ssum, 0, 64) + p_self);

    if (g == 0) {
        // self term + normalize + bias + ELU + W3 dot
        uint2 r = *(const uint2*)(h16 + (size_t)dst * 64 + sub * 4);
        float hv[4]; h4_to_f4(r, hv);
        float4 bv = *(const float4*)&b[sub * 4];
        float4 w3 = *(const float4*)&W3[sub * 4];
        float o0 = (acc[0] + p_self * hv[0]) * inv_s + bv.x;
        float o1 = (acc[1] + p_self * hv[1]) * inv_s + bv.y;
        float o2 = (acc[2] + p_self * hv[2]) * inv_s + bv.z;
        float o3 = (acc[3] + p_self * hv[3]) * inv_s + bv.w;
        o0 = o0 > 0.f ? o0 : expm1f(o0);
        o1 = o1 > 0.f ? o1 : expm1f(o1);
        o2 = o2 > 0.f ? o2 : expm1f(o2);
        o3 = o3 > 0.f ? o3 : expm1f(o3);
        float pp = o0 * w3.x + o1 * w3.y + o2 * w3.z + o3 * w3.w;
        #pragma unroll
        for (int off = 1; off < 16; off <<= 1) pp += __shfl_xor(pp, off, 64);

        if (sub == 0) {
            h3[dst] = pp;
            es3[dst] = pp * a_src3[0];
            ed3[dst] = pp * a_dst3[0];
        }
    }
}

// ---------------- layer 3 edge phase + mean: 16 lanes/dst, grid-stride, 1 atomic/block ----------------
#define MEAN_BLOCKS 200
__global__ void k_gat_edge_c1_mean(const int* __restrict__ row_ptr, const int* __restrict__ csr_src,
                                   const float* __restrict__ h, const float* __restrict__ es,
                                   const float* __restrict__ ed, const float* __restrict__ b3,
                                   float* __restrict__ out) {
    __shared__ float sdata[256];
    const int t = threadIdx.x;
    const int sub = t & 15;
    const int slot = t >> 4;
    const int ntiles = (N_NODES + 15) / 16;
    float local = 0.f;

    for (int tile = blockIdx.x; tile < ntiles; tile += gridDim.x) {
        int dst = tile * 16 + slot;
        if (dst < N_NODES) {
            int beg = dst ? row_ptr[dst - 1] : 0;
            int end = row_ptr[dst];
            float edd = ed[dst];
            float s = 0.f, acc = 0.f;
            for (int k = beg + sub; k < end; k += 16) {
                int src = csr_src[k];
                float pv = __expf(lrelu(es[src] + edd));
                s += pv;
                acc += pv * h[src];
            }
            #pragma unroll
            for (int off = 1; off < 16; off <<= 1) {
                s += __shfl_xor(s, off, 64);
                acc += __shfl_xor(acc, off, 64);
            }
            if (sub == 0) {
                float p = __expf(lrelu(es[dst] + edd));
                s += p;
                acc += p * h[dst];
                local += acc / s;
            }
        }
    }

    sdata[t] = local;
    __syncthreads();
    for (int sft = 128; sft > 0; sft >>= 1) {
        if (t < sft) sdata[t] += sdata[t + sft];
        __syncthreads();
    }
    if (t == 0) {
        float add = sdata[0] / (float)N_NODES;
        if (blockIdx.x == 0) add += b3[0];
        atomicAdd(out, add);
    }
}

extern "C" void kernel_launch(void* const* d_in, const int* in_sizes, int n_in,
                              void* d_out, int out_size, void* d_ws, size_t ws_size,
                              hipStream_t stream) {
    const float* x      = (const float*)d_in[0];
    const float* W1     = (const float*)d_in[1];
    const float* a_src1 = (const float*)d_in[2];
    const float* a_dst1 = (const float*)d_in[3];
    const float* b1     = (const float*)d_in[4];
    const float* W2     = (const float*)d_in[5];
    const float* a_src2 = (const float*)d_in[6];
    const float* a_dst2 = (const float*)d_in[7];
    const float* b2     = (const float*)d_in[8];
    const float* W3     = (const float*)d_in[9];
    const float* a_src3 = (const float*)d_in[10];
    const float* a_dst3 = (const float*)d_in[11];
    const float* b3     = (const float*)d_in[12];
    const int*   ei     = (const int*)d_in[13];
    float* out = (float*)d_out;

    const int BS = 256;
    const size_t N = N_NODES;

    // workspace layout (float units)
    float*  ws      = (float*)d_ws;
    __half* y16     = (__half*)ws;                 // N*128 halves = N*64 floats
    __half* h2_16   = (__half*)(ws + N * 64);      // N*64 halves = N*32 floats
    float*  h3raw   = ws + N * 96;                 // N
    float*  es3     = h3raw + N;                   // N
    float*  ed3     = es3 + N;                     // N
    float*  es_buf  = ed3 + N;                     // N*4
    float*  ed_buf  = es_buf + N * 4;              // N*4
    __half* W1t     = (__half*)(ed_buf + N * 4);   // 512*32 halves = 8192 floats
    __half* W2t     = (__half*)(ed_buf + N * 4 + 8192); // 64*512 halves = 16384 floats
    __half* x16     = (__half*)(ed_buf + N * 4 + 8192 + 16384); // N*21 halves -> N*11 floats
    int*    deg     = (int*)(ed_buf + N * 4 + 8192 + 16384 + N * 11); // N
    int*    row_ptr = deg + N;                     // N (end-pointer convention)
    int*    csr_src = row_ptr + N;                 // E_EDGES
    int*    bsum    = csr_src + E_EDGES;           // 256

    // prep: degree count + layer-1 coef + x->fp16 + weight transposes
    hipMemsetAsync(deg, 0, N * sizeof(int), stream);
    k_prep<<<cdiv(E_EDGES, BS), BS, 0, stream>>>(ei, deg, x, W1, a_src1, a_dst1,
                                                 es_buf, ed_buf, W2, W1t, W2t, x16);

    // CSR scan + end-pointer scatter
    k_scan1<<<SCAN_BLOCKS, 256, 0, stream>>>(deg, bsum);
    k_scan23<<<SCAN_BLOCKS, 256, 0, stream>>>(deg, bsum, row_ptr);
    k_scatter<<<cdiv(E_EDGES, BS), BS, 0, stream>>>(ei, row_ptr, csr_src);

    // Layer 1 edge aggregation (single-pass softmax) on fp16 x
    k_edge_l1x<<<cdiv((long)N * 64, BS), BS, 0, stream>>>(row_ptr, csr_src, x16, es_buf, ed_buf, y16);

    // Fused: out1 = ELU(y@W1+b1) (LDS) then h2 = out1@W2 + es/ed
    k_l12_fused<<<cdiv(N_NODES, 32), 256, 0, stream>>>(y16, W1t, b1, W2t, a_src2, a_dst2, h2_16, es_buf, ed_buf);

    // Layer 2 edge phase (single-pass) with fused layer-3 GEMM + coefficients
    k_gat_edge_l2_l3<<<cdiv((long)N * 64, BS), BS, 0, stream>>>(row_ptr, csr_src, h2_16, es_buf, ed_buf,
                                                                b2, W3, a_src3, a_dst3, h3raw, es3, ed3);

    // Layer 3 edge phase + mean
    hipMemsetAsync(out, 0, sizeof(float), stream);
    k_gat_edge_c1_mean<<<MEAN_BLOCKS, 256, 0, stream>>>(row_ptr, csr_src, h3raw, es3, ed3, b3, out);
}